// Round 1
// baseline (689.457 us; speedup 1.0000x reference)
//
#include <hip/hip_runtime.h>
#include <math.h>

typedef unsigned short u16;
typedef unsigned int u32;
typedef __attribute__((ext_vector_type(8))) short short8;
typedef __attribute__((ext_vector_type(4))) float f32x4;

// ---------------- workspace layout (bytes) ----------------
// planes_t: 3*512*512 texels * 40 bf16 ch (c>=36 zero)   = 62,914,560
// lines_t : 3*512 texels * 40 bf16                        =    122,880
// w1s     : 16 nt * 5 kt * 64 lanes * 8 bf16              =     81,920
// w2s     : 12 nt * 8 kt * 64 lanes * 8 bf16              =     98,304
// total   : 63,217,664
#define OFF_LINES_T 62914560u
#define OFF_W1S     63037440u
#define OFF_W2S     63119360u
#define WS_NEEDED   63217664u

__device__ __forceinline__ float bf_lo(u32 u){ union{u32 i;float f;} v; v.i = u << 16; return v.f; }
__device__ __forceinline__ float bf_hi(u32 u){ union{u32 i;float f;} v; v.i = u & 0xffff0000u; return v.f; }
__device__ __forceinline__ u16 f2bf(float f){ union{float f;u32 i;} v; v.f=f; u32 i=v.i; return (u16)((i + 0x7fffu + ((i>>16)&1u)) >> 16); }
__device__ __forceinline__ u32 pack2bf(float lo, float hi){ return (u32)f2bf(lo) | ((u32)f2bf(hi)<<16); }

// ---------------- kernel 1: plane transpose (C,H,W) f32 -> (H,W,C40) bf16 ----------------
__global__ void k_tp(const float* __restrict__ planes, u16* __restrict__ pt){
  int t = blockIdx.x*256 + threadIdx.x;        // 0 .. 786431  (3*512*512)
  int i = t >> 18;
  int yx = t & 262143;
  const float* src = planes + (size_t)i*9437184 + yx;   // i*36*262144 + y*512 + x
  uint4* dst = reinterpret_cast<uint4*>(pt + (size_t)t*40);
#pragma unroll
  for (int cc=0; cc<5; cc++){
    float v[8];
#pragma unroll
    for (int e=0;e<8;e++){
      int c = cc*8+e;
      v[e] = (c<36) ? src[(size_t)c*262144] : 0.f;
    }
    uint4 o; o.x=pack2bf(v[0],v[1]); o.y=pack2bf(v[2],v[3]); o.z=pack2bf(v[4],v[5]); o.w=pack2bf(v[6],v[7]);
    dst[cc]=o;
  }
}

// ---------------- kernel 2: line transpose (C,L) f32 -> (L,C40) bf16 ----------------
__global__ void k_tl(const float* __restrict__ lines, u16* __restrict__ lt){
  int t = blockIdx.x*256 + threadIdx.x;        // 0 .. 1535 (3*512)
  int i = t >> 9, g = t & 511;
  const float* src = lines + (size_t)i*18432 + g;       // i*36*512 + g
  uint4* dst = reinterpret_cast<uint4*>(lt + (size_t)t*40);
#pragma unroll
  for (int cc=0; cc<5; cc++){
    float v[8];
#pragma unroll
    for (int e=0;e<8;e++){
      int c = cc*8+e;
      v[e] = (c<36) ? src[(size_t)c*512] : 0.f;
    }
    uint4 o; o.x=pack2bf(v[0],v[1]); o.y=pack2bf(v[2],v[3]); o.z=pack2bf(v[4],v[5]); o.w=pack2bf(v[6],v[7]);
    dst[cc]=o;
  }
}

// LDS k'-layout (160 slots): [0..35]=mode0, [36..39]=0, [40..75]=mode1, [76..79]=0,
// [80..115]=mode2, [116..119]=0, [120..140]=PE(21), [141..159]=0.
__device__ __forceinline__ int map_k1(int kp){
  if (kp < 120){ int q = kp/40, r = kp - q*40; return (r<36) ? q*36 + r : -1; }
  if (kp < 141) return kp - 12;   // 108 + (kp-120)
  return -1;
}

// ---------------- kernel 3: W1 (129x256 f32) -> bf16 B-fragments, K remapped/padded to 160 ----------------
__global__ void k_w1(const float* __restrict__ W1, u16* __restrict__ w1s){
  int t = blockIdx.x*256 + threadIdx.x;     // 0..5119 = 80 frags * 64 lanes
  int lane = t & 63;
  int fid = t >> 6;                          // nt*5 + kt
  int nt = fid/5, kt = fid - nt*5;
  int n = nt*16 + (lane & 15);
  int kb = kt*32 + (lane >> 4)*8;
  float v[8];
#pragma unroll
  for (int j=0;j<8;j++){ int k = map_k1(kb+j); v[j] = (k>=0) ? W1[k*256+n] : 0.f; }
  uint4 o; o.x=pack2bf(v[0],v[1]); o.y=pack2bf(v[2],v[3]); o.z=pack2bf(v[4],v[5]); o.w=pack2bf(v[6],v[7]);
  *reinterpret_cast<uint4*>(w1s + (size_t)t*8) = o;
}

// ---------------- kernel 4: W2 (256x129 f32) -> bf16 B-fragments, N padded to 192 ----------------
__global__ void k_w2(const float* __restrict__ W2, u16* __restrict__ w2s){
  int t = blockIdx.x*256 + threadIdx.x;     // 0..6143 = 96 frags * 64 lanes
  int lane = t & 63;
  int fid = t >> 6;                          // nt*8 + kt
  int kb = (fid & 7)*32 + (lane >> 4)*8;
  int n = (fid >> 3)*16 + (lane & 15);
  float v[8];
#pragma unroll
  for (int j=0;j<8;j++){ int k = kb+j; v[j] = (n<129) ? W2[k*129+n] : 0.f; }
  uint4 o; o.x=pack2bf(v[0],v[1]); o.y=pack2bf(v[2],v[3]); o.z=pack2bf(v[4],v[5]); o.w=pack2bf(v[6],v[7]);
  *reinterpret_cast<uint4*>(w2s + (size_t)t*8) = o;
}

// bilinear(plane taps) * lerp(line taps) on 2 packed bf16 channels -> packed bf16
__device__ __forceinline__ u32 blend(u32 u00,u32 u01,u32 u10,u32 u11,u32 g0,u32 g1,
                                     float wx,float wy,float wz){
  float r[2];
#pragma unroll
  for (int h=0; h<2; h++){
    float f00 = h ? bf_hi(u00) : bf_lo(u00);
    float f01 = h ? bf_hi(u01) : bf_lo(u01);
    float f10 = h ? bf_hi(u10) : bf_lo(u10);
    float f11 = h ? bf_hi(u11) : bf_lo(u11);
    float e0  = h ? bf_hi(g0)  : bf_lo(g0);
    float e1  = h ? bf_hi(g1)  : bf_lo(g1);
    float a  = f00 + (f01-f00)*wx;
    float b  = f10 + (f11-f10)*wx;
    float pf = a + (b-a)*wy;
    float lf = e0 + (e1-e0)*wz;
    r[h] = pf*lf;
  }
  return pack2bf(r[0], r[1]);
}

#define FSTRIDE 168   // feature LDS row stride (u16), 336B: 84 dw -> 8-bank/2-way (free)
#define HSTRIDE 264   // H LDS row stride (u16), 528B: 132 dw -> 8-bank/2-way (free)

// ---------------- kernel 5: fused gather + MLP ----------------
__global__ void __launch_bounds__(256) k_main(
    const float* __restrict__ xyz, const u16* __restrict__ pt,
    const u16* __restrict__ lt, const u16* __restrict__ w1s,
    const u16* __restrict__ w2s, const float* __restrict__ b1,
    const float* __restrict__ b2, float* __restrict__ out)
{
  __shared__ u16 smem[64*HSTRIDE];   // 33,792 B; feat-tile (stride 168) aliased by H-tile (stride 264)
  const int tid = threadIdx.x;
  const int p = tid >> 2, q = tid & 3;
  const int gp = blockIdx.x*64 + p;
  const float u0 = xyz[gp*3], u1 = xyz[gp*3+1], u2 = xyz[gp*3+2];
  const float xn0 = 2.f*u0-1.f, xn1 = 2.f*u1-1.f, xn2 = 2.f*u2-1.f;

  if (q < 3){
    // MAT_MODE=[(0,1),(0,2),(1,2)], VEC_MODE=[2,1,0]; x<-m0, y<-m1
    float gxv, gyv, gzv;
    if      (q==0){ gxv=xn0; gyv=xn1; gzv=xn2; }
    else if (q==1){ gxv=xn0; gyv=xn2; gzv=xn1; }
    else          { gxv=xn1; gyv=xn2; gzv=xn0; }
    float px=(gxv+1.0f)*0.5f*511.0f, py=(gyv+1.0f)*0.5f*511.0f, pz=(gzv+1.0f)*0.5f*511.0f;
    float fx=fminf(fmaxf(floorf(px),0.f),510.f);
    float fy=fminf(fmaxf(floorf(py),0.f),510.f);
    float fz=fminf(fmaxf(floorf(pz),0.f),510.f);
    int ix=(int)fx, iy=(int)fy, iz=(int)fz;
    float wx=px-fx, wy=py-fy, wz=pz-fz;
    const u16* base  = pt + (size_t)((q<<18)+(iy<<9)+ix)*40;
    const u16* lbase = lt + (size_t)((q<<9)+iz)*40;
    u16* dst = smem + p*FSTRIDE + q*40;
#pragma unroll
    for (int cc=0; cc<5; cc++){
      const uint4 a00 = *reinterpret_cast<const uint4*>(base + cc*8);
      const uint4 a01 = *reinterpret_cast<const uint4*>(base + 40 + cc*8);
      const uint4 a10 = *reinterpret_cast<const uint4*>(base + 20480 + cc*8);
      const uint4 a11 = *reinterpret_cast<const uint4*>(base + 20520 + cc*8);
      const uint4 e0  = *reinterpret_cast<const uint4*>(lbase + cc*8);
      const uint4 e1  = *reinterpret_cast<const uint4*>(lbase + 40 + cc*8);
      uint4 o;
      o.x = blend(a00.x,a01.x,a10.x,a11.x,e0.x,e1.x,wx,wy,wz);
      o.y = blend(a00.y,a01.y,a10.y,a11.y,e0.y,e1.y,wx,wy,wz);
      o.z = blend(a00.z,a01.z,a10.z,a11.z,e0.z,e1.z,wx,wy,wz);
      o.w = blend(a00.w,a01.w,a10.w,a11.w,e0.w,e1.w,wx,wy,wz);
      *reinterpret_cast<uint4*>(dst + cc*8) = o;
    }
  } else {
    // positional encoding: [x(3), sin(x), cos(x), sin(2x), cos(2x), sin(4x), cos(4x)]
    float v[21];
    v[0]=xn0; v[1]=xn1; v[2]=xn2;
    v[3]=__sinf(xn0);      v[4]=__sinf(xn1);      v[5]=__sinf(xn2);
    v[6]=__cosf(xn0);      v[7]=__cosf(xn1);      v[8]=__cosf(xn2);
    v[9]=__sinf(2.f*xn0);  v[10]=__sinf(2.f*xn1); v[11]=__sinf(2.f*xn2);
    v[12]=__cosf(2.f*xn0); v[13]=__cosf(2.f*xn1); v[14]=__cosf(2.f*xn2);
    v[15]=__sinf(4.f*xn0); v[16]=__sinf(4.f*xn1); v[17]=__sinf(4.f*xn2);
    v[18]=__cosf(4.f*xn0); v[19]=__cosf(4.f*xn1); v[20]=__cosf(4.f*xn2);
    u16* dst = smem + p*FSTRIDE + 120;
#pragma unroll
    for (int cc=0; cc<5; cc++){
      float w0 = (cc*8+0<21)?v[cc*8+0]:0.f; float w1v=(cc*8+1<21)?v[cc*8+1]:0.f;
      float w2v= (cc*8+2<21)?v[cc*8+2]:0.f; float w3 =(cc*8+3<21)?v[cc*8+3]:0.f;
      float w4 = (cc*8+4<21)?v[cc*8+4]:0.f; float w5 =(cc*8+5<21)?v[cc*8+5]:0.f;
      float w6 = (cc*8+6<21)?v[cc*8+6]:0.f; float w7 =(cc*8+7<21)?v[cc*8+7]:0.f;
      uint4 o; o.x=pack2bf(w0,w1v); o.y=pack2bf(w2v,w3); o.z=pack2bf(w4,w5); o.w=pack2bf(w6,w7);
      *reinterpret_cast<uint4*>(dst + cc*8) = o;
    }
  }
  __syncthreads();

  // ---- stage 1: H = softplus(100*(feat@W1+b1))/100, M=64 K=160 N=256 ----
  const int lane = tid & 63;
  const int w = tid >> 6;
  const int lm = lane & 15;
  const int quad = lane >> 4;
  const f32x4 zero = {0.f,0.f,0.f,0.f};
  f32x4 acc1[4][4];
#pragma unroll
  for (int mt=0; mt<4; mt++)
#pragma unroll
    for (int nt=0; nt<4; nt++) acc1[mt][nt] = zero;

#pragma unroll
  for (int kt=0; kt<5; kt++){
    short8 a[4];
#pragma unroll
    for (int mt=0; mt<4; mt++)
      a[mt] = *reinterpret_cast<const short8*>(smem + (mt*16 + lm)*FSTRIDE + kt*32 + quad*8);
    short8 b[4];
#pragma unroll
    for (int nt=0; nt<4; nt++)
      b[nt] = *reinterpret_cast<const short8*>(w1s + (size_t)(((w*4+nt)*5 + kt)*64 + lane)*8);
#pragma unroll
    for (int mt=0; mt<4; mt++)
#pragma unroll
      for (int nt=0; nt<4; nt++)
        acc1[mt][nt] = __builtin_amdgcn_mfma_f32_16x16x32_bf16(a[mt], b[nt], acc1[mt][nt], 0,0,0);
  }
  __syncthreads();   // all feat reads done before H overwrites the same LDS

#pragma unroll
  for (int nt=0; nt<4; nt++){
    int col = w*64 + nt*16 + lm;
    float bias = b1[col];
#pragma unroll
    for (int mt=0; mt<4; mt++){
#pragma unroll
      for (int r=0; r<4; r++){
        float xv = acc1[mt][nt][r] + bias;
        float z = 100.f*xv;
        float y = (z > 15.f) ? xv : __logf(1.f + __expf(z))*0.01f;
        int row = mt*16 + quad*4 + r;
        smem[row*HSTRIDE + col] = f2bf(y);
      }
    }
  }
  __syncthreads();

  // ---- stage 2: out = H@W2 + b2, M=64 K=256 N=144(->192 padded) ----
  f32x4 acc2[4][3];
#pragma unroll
  for (int mt=0; mt<4; mt++)
#pragma unroll
    for (int nt=0; nt<3; nt++) acc2[mt][nt] = zero;

#pragma unroll
  for (int kt=0; kt<8; kt++){
    short8 a[4];
#pragma unroll
    for (int mt=0; mt<4; mt++)
      a[mt] = *reinterpret_cast<const short8*>(smem + (mt*16 + lm)*HSTRIDE + kt*32 + quad*8);
    short8 b[3];
#pragma unroll
    for (int nt=0; nt<3; nt++){
      int ntg = w + nt*4;
      b[nt] = *reinterpret_cast<const short8*>(w2s + (size_t)((ntg*8 + kt)*64 + lane)*8);
    }
#pragma unroll
    for (int mt=0; mt<4; mt++)
#pragma unroll
      for (int nt=0; nt<3; nt++)
        acc2[mt][nt] = __builtin_amdgcn_mfma_f32_16x16x32_bf16(a[mt], b[nt], acc2[mt][nt], 0,0,0);
  }

#pragma unroll
  for (int nt=0; nt<3; nt++){
    int j = (w + nt*4)*16 + lm;
    if (j < 129){
      float bias = b2[j];
#pragma unroll
      for (int mt=0; mt<4; mt++){
#pragma unroll
        for (int r=0; r<4; r++){
          int row = mt*16 + quad*4 + r;
          out[(size_t)(blockIdx.x*64 + row)*129 + j] = acc2[mt][nt][r] + bias;
        }
      }
    }
  }
}

extern "C" void kernel_launch(void* const* d_in, const int* in_sizes, int n_in,
                              void* d_out, int out_size, void* d_ws, size_t ws_size,
                              hipStream_t stream) {
  const float* xyz    = (const float*)d_in[0];
  const float* planes = (const float*)d_in[1];
  const float* lines  = (const float*)d_in[2];
  const float* W1     = (const float*)d_in[3];
  const float* b1     = (const float*)d_in[4];
  const float* W2     = (const float*)d_in[5];
  const float* b2     = (const float*)d_in[6];
  if (ws_size < (size_t)WS_NEEDED) return;   // workspace too small: fail loudly (validation will show it)

  u16* pt  = (u16*)((char*)d_ws);
  u16* lt  = (u16*)((char*)d_ws + OFF_LINES_T);
  u16* w1s = (u16*)((char*)d_ws + OFF_W1S);
  u16* w2s = (u16*)((char*)d_ws + OFF_W2S);

  k_tp<<<3072, 256, 0, stream>>>(planes, pt);
  k_tl<<<6,    256, 0, stream>>>(lines,  lt);
  k_w1<<<20,   256, 0, stream>>>(W1, w1s);
  k_w2<<<24,   256, 0, stream>>>(W2, w2s);
  k_main<<<8192, 256, 0, stream>>>(xyz, pt, lt, w1s, w2s, b1, b2, (float*)d_out);
}

// Round 3
// 656.081 us; speedup vs baseline: 1.0509x; 1.0509x over previous
//
#include <hip/hip_runtime.h>
#include <math.h>

typedef unsigned short u16;
typedef unsigned int u32;
typedef __attribute__((ext_vector_type(2))) u32 u32x2;
typedef __attribute__((ext_vector_type(8))) short short8;
typedef __attribute__((ext_vector_type(4))) float f32x4;

// ---------------- workspace layout (bytes) ----------------
// planes_t: 3*512*512 texels * 40 bf16 ch (c>=36 zero)   = 62,914,560
// lines_t : 3*512 texels * 40 bf16                        =    122,880
// w1s     : 16 nt * 5 kt * 64 lanes * 8 bf16              =     81,920
// w2s     : 12 nt * 8 kt * 64 lanes * 8 bf16              =     98,304
#define OFF_LINES_T 62914560u
#define OFF_W1S     63037440u
#define OFF_W2S     63119360u
#define WS_NEEDED   63217664u

__device__ __forceinline__ float bf_lo(u32 u){ union{u32 i;float f;} v; v.i = u << 16; return v.f; }
__device__ __forceinline__ float bf_hi(u32 u){ union{u32 i;float f;} v; v.i = u & 0xffff0000u; return v.f; }
// RTNE pack (precompute kernels only — cost irrelevant there)
__device__ __forceinline__ u16 f2bf(float f){ union{float f;u32 i;} v; v.f=f; u32 i=v.i; return (u16)((i + 0x7fffu + ((i>>16)&1u)) >> 16); }
__device__ __forceinline__ u32 pack2bf(float lo, float hi){ return (u32)f2bf(lo) | ((u32)f2bf(hi)<<16); }
// fast round-half-up pack: 2 adds + v_perm (vs ~9 inst RTNE); error <= 0.5 ulp
__device__ __forceinline__ u32 pack2bf_fast(float lo, float hi){
  return __builtin_amdgcn_perm(__float_as_uint(hi) + 0x8000u,
                               __float_as_uint(lo) + 0x8000u, 0x07060302u);
}
__device__ __forceinline__ u16 f2bf_fast(float f){ return (u16)((__float_as_uint(f) + 0x8000u) >> 16); }

// ---------------- kernel 1: plane transpose (C,H,W) f32 -> (H,W,C40) bf16 ----------------
__global__ void k_tp(const float* __restrict__ planes, u16* __restrict__ pt){
  int t = blockIdx.x*256 + threadIdx.x;        // 0 .. 786431  (3*512*512)
  int i = t >> 18;
  int yx = t & 262143;
  const float* src = planes + (size_t)i*9437184 + yx;   // i*36*262144 + y*512 + x
  uint4* dst = reinterpret_cast<uint4*>(pt + (size_t)t*40);
#pragma unroll
  for (int cc=0; cc<5; cc++){
    float v[8];
#pragma unroll
    for (int e=0;e<8;e++){
      int c = cc*8+e;
      v[e] = (c<36) ? src[(size_t)c*262144] : 0.f;
    }
    uint4 o; o.x=pack2bf(v[0],v[1]); o.y=pack2bf(v[2],v[3]); o.z=pack2bf(v[4],v[5]); o.w=pack2bf(v[6],v[7]);
    dst[cc]=o;
  }
}

// ---------------- kernel 2: line transpose (C,L) f32 -> (L,C40) bf16 ----------------
__global__ void k_tl(const float* __restrict__ lines, u16* __restrict__ lt){
  int t = blockIdx.x*256 + threadIdx.x;        // 0 .. 1535 (3*512)
  int i = t >> 9, g = t & 511;
  const float* src = lines + (size_t)i*18432 + g;       // i*36*512 + g
  uint4* dst = reinterpret_cast<uint4*>(lt + (size_t)t*40);
#pragma unroll
  for (int cc=0; cc<5; cc++){
    float v[8];
#pragma unroll
    for (int e=0;e<8;e++){
      int c = cc*8+e;
      v[e] = (c<36) ? src[(size_t)c*512] : 0.f;
    }
    uint4 o; o.x=pack2bf(v[0],v[1]); o.y=pack2bf(v[2],v[3]); o.z=pack2bf(v[4],v[5]); o.w=pack2bf(v[6],v[7]);
    dst[cc]=o;
  }
}

// LDS k'-layout (160 slots): [0..35]=mode0, [36..39]=0, [40..75]=mode1, [76..79]=0,
// [80..115]=mode2, [116..119]=0, [120..140]=PE(21), [141..159]=0.
__device__ __forceinline__ int map_k1(int kp){
  if (kp < 120){ int g = kp/40, r = kp - g*40; return (r<36) ? g*36 + r : -1; }
  if (kp < 141) return kp - 12;   // 108 + (kp-120)
  return -1;
}

// ---------------- kernel 3: W1 (129x256 f32) -> bf16 B-fragments, K remapped/padded to 160 ----------------
__global__ void k_w1(const float* __restrict__ W1, u16* __restrict__ w1s){
  int t = blockIdx.x*256 + threadIdx.x;     // 0..5119 = 80 frags * 64 lanes
  int lane = t & 63;
  int fid = t >> 6;                          // nt*5 + kt
  int nt = fid/5, kt = fid - nt*5;
  int n = nt*16 + (lane & 15);
  int kb = kt*32 + (lane >> 4)*8;
  float v[8];
#pragma unroll
  for (int j=0;j<8;j++){ int k = map_k1(kb+j); v[j] = (k>=0) ? W1[k*256+n] : 0.f; }
  uint4 o; o.x=pack2bf(v[0],v[1]); o.y=pack2bf(v[2],v[3]); o.z=pack2bf(v[4],v[5]); o.w=pack2bf(v[6],v[7]);
  *reinterpret_cast<uint4*>(w1s + (size_t)t*8) = o;
}

// ---------------- kernel 4: W2 (256x129 f32) -> bf16 B-fragments, N padded to 192 ----------------
__global__ void k_w2(const float* __restrict__ W2, u16* __restrict__ w2s){
  int t = blockIdx.x*256 + threadIdx.x;     // 0..6143 = 96 frags * 64 lanes
  int lane = t & 63;
  int fid = t >> 6;                          // nt*8 + kt
  int kb = (fid & 7)*32 + (lane >> 4)*8;
  int n = (fid >> 3)*16 + (lane & 15);
  float v[8];
#pragma unroll
  for (int j=0;j<8;j++){ int k = kb+j; v[j] = (n<129) ? W2[k*129+n] : 0.f; }
  uint4 o; o.x=pack2bf(v[0],v[1]); o.y=pack2bf(v[2],v[3]); o.z=pack2bf(v[4],v[5]); o.w=pack2bf(v[6],v[7]);
  *reinterpret_cast<uint4*>(w2s + (size_t)t*8) = o;
}

// bilinear(plane taps) * lerp(line taps) on 2 packed bf16 channels -> packed bf16
__device__ __forceinline__ u32 blend(u32 u00,u32 u01,u32 u10,u32 u11,u32 g0,u32 g1,
                                     float wx,float wy,float wz){
  float r[2];
#pragma unroll
  for (int h=0; h<2; h++){
    float f00 = h ? bf_hi(u00) : bf_lo(u00);
    float f01 = h ? bf_hi(u01) : bf_lo(u01);
    float f10 = h ? bf_hi(u10) : bf_lo(u10);
    float f11 = h ? bf_hi(u11) : bf_lo(u11);
    float e0  = h ? bf_hi(g0)  : bf_lo(g0);
    float e1  = h ? bf_hi(g1)  : bf_lo(g1);
    float a  = f00 + (f01-f00)*wx;
    float b  = f10 + (f11-f10)*wx;
    float pf = a + (b-a)*wy;
    float lf = e0 + (e1-e0)*wz;
    r[h] = pf*lf;
  }
  return pack2bf_fast(r[0], r[1]);
}

#define FSTRIDE 168   // feature LDS row stride (u16), 336B: 84 dw -> 2-way bank alias only (free)
#define HSTRIDE 264   // H LDS row stride (u16), 528B: 132 dw -> 2-way alias only (free)

// ---------------- kernel 5: fused gather + MLP ----------------
// 512 threads = 8 waves, 64 points/block. 8 threads/point: q=0..5 gather
// (plane q>>1, 20-slot half q&1), q=6 positional encoding (ALL 40 slots
// 120..159 — slots 140..159 MUST be written: uninit LDS NaN x zero-weight
// still poisons the MFMA accumulator; this was the R2 NaN), q=7 idle.
// Wave grid for MFMA: wm=w&1, wn=w>>1. acc pressure: stage1 acc[2][4]=32,
// stage2 acc[2][3]=24 -> combined VGPR+ACC fits 128 => 4 waves/SIMD.
__global__ void __launch_bounds__(512, 4) k_main(
    const float* __restrict__ xyz, const u16* __restrict__ pt,
    const u16* __restrict__ lt, const u16* __restrict__ w1s,
    const u16* __restrict__ w2s, const float* __restrict__ b1,
    const float* __restrict__ b2, float* __restrict__ out)
{
  __shared__ u16 smem[64*HSTRIDE];   // 33,792 B; feat-tile (stride 168) aliased by H-tile (stride 264)
  const int tid = threadIdx.x;
  const int p = tid >> 3, q = tid & 7;
  const int gp = blockIdx.x*64 + p;
  const float u0 = xyz[gp*3], u1 = xyz[gp*3+1], u2 = xyz[gp*3+2];
  const float xn0 = 2.f*u0-1.f, xn1 = 2.f*u1-1.f, xn2 = 2.f*u2-1.f;

  if (q < 6){
    const int i = q >> 1, part = q & 1;
    // MAT_MODE=[(0,1),(0,2),(1,2)], VEC_MODE=[2,1,0]; x<-m0, y<-m1
    float gxv, gyv, gzv;
    if      (i==0){ gxv=xn0; gyv=xn1; gzv=xn2; }
    else if (i==1){ gxv=xn0; gyv=xn2; gzv=xn1; }
    else          { gxv=xn1; gyv=xn2; gzv=xn0; }
    float px=(gxv+1.0f)*0.5f*511.0f, py=(gyv+1.0f)*0.5f*511.0f, pz=(gzv+1.0f)*0.5f*511.0f;
    float fx=fminf(fmaxf(floorf(px),0.f),510.f);
    float fy=fminf(fmaxf(floorf(py),0.f),510.f);
    float fz=fminf(fmaxf(floorf(pz),0.f),510.f);
    int ix=(int)fx, iy=(int)fy, iz=(int)fz;
    float wx=px-fx, wy=py-fy, wz=pz-fz;
    const u16* base  = pt + (size_t)((i<<18)+(iy<<9)+ix)*40 + part*20;
    const u16* lbase = lt + (size_t)((i<<9)+iz)*40 + part*20;
    u16* dst = smem + p*FSTRIDE + i*40 + part*20;
#pragma unroll
    for (int c=0; c<5; c++){
      u32x2 a00 = *reinterpret_cast<const u32x2*>(base + c*4);
      u32x2 a01 = *reinterpret_cast<const u32x2*>(base + 40 + c*4);
      u32x2 a10 = *reinterpret_cast<const u32x2*>(base + 20480 + c*4);
      u32x2 a11 = *reinterpret_cast<const u32x2*>(base + 20520 + c*4);
      u32x2 e0  = *reinterpret_cast<const u32x2*>(lbase + c*4);
      u32x2 e1  = *reinterpret_cast<const u32x2*>(lbase + 40 + c*4);
      u32x2 o;
      o.x = blend(a00.x,a01.x,a10.x,a11.x,e0.x,e1.x,wx,wy,wz);
      o.y = blend(a00.y,a01.y,a10.y,a11.y,e0.y,e1.y,wx,wy,wz);
      *reinterpret_cast<u32x2*>(dst + c*4) = o;
    }
  } else if (q == 6){
    // positional encoding: [x(3), sin(x), cos(x), sin(2x), cos(2x), sin(4x), cos(4x)]
    // -> slots 120..140, explicit zeros through 159 (20 u32 writes = 40 slots)
    float v[21];
    v[0]=xn0; v[1]=xn1; v[2]=xn2;
    v[3]=__sinf(xn0);      v[4]=__sinf(xn1);      v[5]=__sinf(xn2);
    v[6]=__cosf(xn0);      v[7]=__cosf(xn1);      v[8]=__cosf(xn2);
    v[9]=__sinf(2.f*xn0);  v[10]=__sinf(2.f*xn1); v[11]=__sinf(2.f*xn2);
    v[12]=__cosf(2.f*xn0); v[13]=__cosf(2.f*xn1); v[14]=__cosf(2.f*xn2);
    v[15]=__sinf(4.f*xn0); v[16]=__sinf(4.f*xn1); v[17]=__sinf(4.f*xn2);
    v[18]=__cosf(4.f*xn0); v[19]=__cosf(4.f*xn1); v[20]=__cosf(4.f*xn2);
    u16* dst = smem + p*FSTRIDE + 120;
#pragma unroll
    for (int c=0; c<20; c++){
      float a = (c*2  <21)?v[c*2  ]:0.f;
      float b = (c*2+1<21)?v[c*2+1]:0.f;
      *reinterpret_cast<u32*>(dst + c*2) = pack2bf_fast(a,b);
    }
  }
  __syncthreads();

  // ---- stage 1: H = softplus(100*(feat@W1+b1))/100, M=64 K=160 N=256 ----
  const int lane = tid & 63;
  const int w = tid >> 6;            // 0..7
  const int wm = w & 1, wn = w >> 1; // 2 m-tiles x 4 n-tiles per wave
  const int lm = lane & 15;
  const int quad = lane >> 4;
  const f32x4 zero = {0.f,0.f,0.f,0.f};
  f32x4 acc1[2][4];
#pragma unroll
  for (int mt=0; mt<2; mt++)
#pragma unroll
    for (int nt=0; nt<4; nt++) acc1[mt][nt] = zero;

#pragma unroll
  for (int kt=0; kt<5; kt++){
    short8 a[2];
#pragma unroll
    for (int mt=0; mt<2; mt++)
      a[mt] = *reinterpret_cast<const short8*>(smem + ((wm*2+mt)*16 + lm)*FSTRIDE + kt*32 + quad*8);
    short8 b[4];
#pragma unroll
    for (int nt=0; nt<4; nt++)
      b[nt] = *reinterpret_cast<const short8*>(w1s + (size_t)(((wn*4+nt)*5 + kt)*64 + lane)*8);
#pragma unroll
    for (int mt=0; mt<2; mt++)
#pragma unroll
      for (int nt=0; nt<4; nt++)
        acc1[mt][nt] = __builtin_amdgcn_mfma_f32_16x16x32_bf16(a[mt], b[nt], acc1[mt][nt], 0,0,0);
  }
  __syncthreads();   // all feat reads done before H overwrites the same LDS

#pragma unroll
  for (int nt=0; nt<4; nt++){
    int col = wn*64 + nt*16 + lm;
    float bias = b1[col];
#pragma unroll
    for (int mt=0; mt<2; mt++){
#pragma unroll
      for (int r=0; r<4; r++){
        float xv = acc1[mt][nt][r] + bias;
        float z = 100.f*xv;
        float y = (z > 15.f) ? xv : __logf(1.f + __expf(z))*0.01f;
        int row = (wm*2+mt)*16 + quad*4 + r;
        smem[row*HSTRIDE + col] = f2bf_fast(y);
      }
    }
  }
  __syncthreads();

  // ---- stage 2: out = H@W2 + b2, M=64 K=256 N=144(->192 padded) ----
  f32x4 acc2[2][3];
#pragma unroll
  for (int mt=0; mt<2; mt++)
#pragma unroll
    for (int nt=0; nt<3; nt++) acc2[mt][nt] = zero;

#pragma unroll
  for (int kt=0; kt<8; kt++){
    short8 a[2];
#pragma unroll
    for (int mt=0; mt<2; mt++)
      a[mt] = *reinterpret_cast<const short8*>(smem + ((wm*2+mt)*16 + lm)*HSTRIDE + kt*32 + quad*8);
    short8 b[3];
#pragma unroll
    for (int nt=0; nt<3; nt++){
      int ntg = wn*3 + nt;
      b[nt] = *reinterpret_cast<const short8*>(w2s + (size_t)((ntg*8 + kt)*64 + lane)*8);
    }
#pragma unroll
    for (int mt=0; mt<2; mt++)
#pragma unroll
      for (int nt=0; nt<3; nt++)
        acc2[mt][nt] = __builtin_amdgcn_mfma_f32_16x16x32_bf16(a[mt], b[nt], acc2[mt][nt], 0,0,0);
  }

#pragma unroll
  for (int nt=0; nt<3; nt++){
    int j = (wn*3 + nt)*16 + lm;
    if (j < 129){
      float bias = b2[j];
#pragma unroll
      for (int mt=0; mt<2; mt++){
#pragma unroll
        for (int r=0; r<4; r++){
          int row = (wm*2+mt)*16 + quad*4 + r;
          out[(size_t)(blockIdx.x*64 + row)*129 + j] = acc2[mt][nt][r] + bias;
        }
      }
    }
  }
}

extern "C" void kernel_launch(void* const* d_in, const int* in_sizes, int n_in,
                              void* d_out, int out_size, void* d_ws, size_t ws_size,
                              hipStream_t stream) {
  const float* xyz    = (const float*)d_in[0];
  const float* planes = (const float*)d_in[1];
  const float* lines  = (const float*)d_in[2];
  const float* W1     = (const float*)d_in[3];
  const float* b1     = (const float*)d_in[4];
  const float* W2     = (const float*)d_in[5];
  const float* b2     = (const float*)d_in[6];
  if (ws_size < (size_t)WS_NEEDED) return;   // workspace too small: fail loudly (validation will show it)

  u16* pt  = (u16*)((char*)d_ws);
  u16* lt  = (u16*)((char*)d_ws + OFF_LINES_T);
  u16* w1s = (u16*)((char*)d_ws + OFF_W1S);
  u16* w2s = (u16*)((char*)d_ws + OFF_W2S);

  k_tp<<<3072, 256, 0, stream>>>(planes, pt);
  k_tl<<<6,    256, 0, stream>>>(lines,  lt);
  k_w1<<<20,   256, 0, stream>>>(W1, w1s);
  k_w2<<<24,   256, 0, stream>>>(W2, w2s);
  k_main<<<8192, 512, 0, stream>>>(xyz, pt, lt, w1s, w2s, b1, b2, (float*)d_out);
}